// Round 4
// baseline (105.464 us; speedup 1.0000x reference)
//
#include <hip/hip_runtime.h>

typedef __attribute__((ext_vector_type(4))) _Float16 half4;
typedef __attribute__((ext_vector_type(8))) _Float16 half8;
typedef __attribute__((ext_vector_type(4))) float f32x4;

#define T_STEPS 24
#define N_NODES 325
#define RS_T 20800       // N*H elements per t
#define B_STRIDE 499200  // T*N*H elements per b
#define HLAST_OFF 31948800

__device__ __forceinline__ float fsigmoid(float x) {
    return __builtin_amdgcn_rcpf(1.0f + __expf(-x));
}
__device__ __forceinline__ float ftanh_f(float x) {
    return 1.0f - 2.0f * __builtin_amdgcn_rcpf(1.0f + __expf(2.0f * x));
}
__device__ __forceinline__ half4 cvt4(f32x4 a) {
    half4 r;
    r[0] = (_Float16)a[0]; r[1] = (_Float16)a[1];
    r[2] = (_Float16)a[2]; r[3] = (_Float16)a[3];
    return r;
}
__device__ __forceinline__ half8 cvt8(f32x4 a, f32x4 b) {
    half8 r;
    r[0]=(_Float16)a[0]; r[1]=(_Float16)a[1]; r[2]=(_Float16)a[2]; r[3]=(_Float16)a[3];
    r[4]=(_Float16)b[0]; r[5]=(_Float16)b[1]; r[6]=(_Float16)b[2]; r[7]=(_Float16)b[3];
    return r;
}

// Swapped-operand GRU: D = W · h^T. One 64-thread wave owns 16 batch rows and
// all 192 gate columns. D-frag layout (col=m, row=4kg+reg) == B-frag layout
// (col=m, k=4kg+i) for the K=16 h-side MFMA, so h_new recycles lane-locally:
// NO LDS, NO barriers, NO cross-lane traffic in the recurrence.
__global__ __launch_bounds__(64, 1) void gru_swapped_kernel(
    const float* __restrict__ data,   // [B,T,N,F]
    const float* __restrict__ h0,     // [B,N,H]
    const float* __restrict__ w_ih,   // [192,64]
    const float* __restrict__ w_hh,   // [192,64]
    const float* __restrict__ b_ih,   // [192]
    const float* __restrict__ b_hh,   // [192]
    float* __restrict__ out)          // [B,T,N,H] ++ [B,N,H]
{
    const int lane = threadIdx.x;     // 0..63
    const int cl   = lane & 15;       // batch row m (B/D col); weight row n (A row)
    const int kg   = lane >> 4;       // k-group / D-row group
    const int row0 = blockIdx.x * 16;

    const int m  = row0 + cl;
    const int mb = m / N_NODES, mn = m % N_NODES;
    const int xybase = mb * B_STRIDE + mn * 64;   // row base in data AND out (F==H==64)

    // ---- weights as swapped A-frags (lane holds W[n=16p+cl][k]) ----
    half4 whh[12][4];   // K=16 slices: k = 16s + 4kg + i
    half8 wih[12][2];   // K=32 slices: k = 32s + 8kg + i
#pragma unroll
    for (int p = 0; p < 12; ++p) {
        const float* wr = w_hh + (p * 16 + cl) * 64;
#pragma unroll
        for (int s = 0; s < 4; ++s)
            whh[p][s] = cvt4(*(const f32x4*)(wr + s * 16 + kg * 4));
        const float* wr2 = w_ih + (p * 16 + cl) * 64;
#pragma unroll
        for (int s = 0; s < 2; ++s)
            wih[p][s] = cvt8(*(const f32x4*)(wr2 + s * 32 + kg * 8),
                             *(const f32x4*)(wr2 + s * 32 + kg * 8 + 4));
    }

    // ---- bias tiles in D layout (n = 16j + 4kg + q) -> MFMA C-operand init ----
    f32x4 bcr[4], bcz[4], bnx[4], bnh[4];
#pragma unroll
    for (int j = 0; j < 4; ++j) {
        const int o = j * 16 + kg * 4;
        const f32x4 bi0 = *(const f32x4*)(b_ih + o);
        const f32x4 bh0 = *(const f32x4*)(b_hh + o);
        const f32x4 bi1 = *(const f32x4*)(b_ih + 64 + o);
        const f32x4 bh1 = *(const f32x4*)(b_hh + 64 + o);
        bcr[j] = bi0 + bh0;
        bcz[j] = bi1 + bh1;
        bnx[j] = *(const f32x4*)(b_ih + 128 + o);
        bnh[j] = *(const f32x4*)(b_hh + 128 + o);
    }

    // ---- h state: f32 master copy + f16 B-frags (lane holds h[m][16j+4kg+q]) ----
    f32x4 hF[4];
    half4 hB[4];
#pragma unroll
    for (int j = 0; j < 4; ++j) {
        hF[j] = *(const f32x4*)(h0 + m * 64 + j * 16 + kg * 4);
        hB[j] = cvt4(hF[j]);
    }

    // ---- x prefetch, 2 steps deep. slot q: offset (q>>1)*32 + kg*8 + (q&1)*4 ----
    f32x4 xfa[4], xfb[4];
#pragma unroll
    for (int q = 0; q < 4; ++q)
        xfa[q] = *(const f32x4*)(data + xybase + (q >> 1) * 32 + kg * 8 + (q & 1) * 4);
#pragma unroll
    for (int q = 0; q < 4; ++q)
        xfb[q] = *(const f32x4*)(data + xybase + RS_T + (q >> 1) * 32 + kg * 8 + (q & 1) * 4);

    auto STEP = [&](int t_cur, int t_load, f32x4 (&xf)[4]) {
        // x A... B-frags for this step, then reuse xf for the t+2 prefetch
        const half8 xh0 = cvt8(xf[0], xf[1]);
        const half8 xh1 = cvt8(xf[2], xf[3]);
#pragma unroll
        for (int q = 0; q < 4; ++q)
            xf[q] = *(const f32x4*)(data + xybase + t_load * RS_T +
                                    (q >> 1) * 32 + kg * 8 + (q & 1) * 4);

        // 16 accumulator tiles; bias enters as C of the first MFMA in each chain
        f32x4 aR[4], aZ[4], aNX[4], aNH[4];
#pragma unroll
        for (int j = 0; j < 4; ++j) {
            aR[j]  = __builtin_amdgcn_mfma_f32_16x16x32_f16(wih[j][0],     xh0, bcr[j], 0, 0, 0);
            aZ[j]  = __builtin_amdgcn_mfma_f32_16x16x32_f16(wih[4 + j][0], xh0, bcz[j], 0, 0, 0);
            aNX[j] = __builtin_amdgcn_mfma_f32_16x16x32_f16(wih[8 + j][0], xh0, bnx[j], 0, 0, 0);
        }
#pragma unroll
        for (int j = 0; j < 4; ++j) {
            aR[j]  = __builtin_amdgcn_mfma_f32_16x16x32_f16(wih[j][1],     xh1, aR[j],  0, 0, 0);
            aZ[j]  = __builtin_amdgcn_mfma_f32_16x16x32_f16(wih[4 + j][1], xh1, aZ[j],  0, 0, 0);
            aNX[j] = __builtin_amdgcn_mfma_f32_16x16x32_f16(wih[8 + j][1], xh1, aNX[j], 0, 0, 0);
        }
        // h-side, K=16 chains; B-operand IS last step's D-frag (hB)
#pragma unroll
        for (int j = 0; j < 4; ++j)
            aNH[j] = __builtin_amdgcn_mfma_f32_16x16x16f16(whh[8 + j][0], hB[0], bnh[j], 0, 0, 0);
#pragma unroll
        for (int s = 0; s < 4; ++s) {
#pragma unroll
            for (int j = 0; j < 4; ++j) {
                aR[j] = __builtin_amdgcn_mfma_f32_16x16x16f16(whh[j][s],     hB[s], aR[j], 0, 0, 0);
                aZ[j] = __builtin_amdgcn_mfma_f32_16x16x16f16(whh[4 + j][s], hB[s], aZ[j], 0, 0, 0);
                if (s > 0)
                    aNH[j] = __builtin_amdgcn_mfma_f32_16x16x16f16(whh[8 + j][s], hB[s], aNH[j], 0, 0, 0);
            }
        }

        // gates + state update + store (all in D layout, lane-local)
#pragma unroll
        for (int j = 0; j < 4; ++j) {
            f32x4 hn;
#pragma unroll
            for (int q = 0; q < 4; ++q) {
                const float rg = fsigmoid(aR[j][q]);
                const float zg = fsigmoid(aZ[j][q]);
                const float cd = ftanh_f(aNX[j][q] + rg * aNH[j][q]);
                hn[q] = cd + zg * (hF[j][q] - cd);
            }
            hF[j] = hn;
            *(f32x4*)(out + xybase + t_cur * RS_T + j * 16 + kg * 4) = hn;
            hB[j] = cvt4(hn);
        }
    };

#pragma unroll 1
    for (int t = 0; t < T_STEPS; t += 2) {
        const int tl0 = (t + 2 < T_STEPS) ? t + 2 : T_STEPS - 1;
        STEP(t, tl0, xfa);
        const int tl1 = (t + 3 < T_STEPS) ? t + 3 : T_STEPS - 1;
        STEP(t + 1, tl1, xfb);
    }

    // h_last
#pragma unroll
    for (int j = 0; j < 4; ++j)
        *(f32x4*)(out + HLAST_OFF + m * 64 + j * 16 + kg * 4) = hF[j];
}

extern "C" void kernel_launch(void* const* d_in, const int* in_sizes, int n_in,
                              void* d_out, int out_size, void* d_ws, size_t ws_size,
                              hipStream_t stream) {
    const float* data = (const float*)d_in[1];
    const float* h0   = (const float*)d_in[2];
    const float* w_ih = (const float*)d_in[3];
    const float* w_hh = (const float*)d_in[4];
    const float* b_ih = (const float*)d_in[5];
    const float* b_hh = (const float*)d_in[6];
    float* out = (float*)d_out;

    // 20800 rows / 16 per wave-block = 1300 blocks of 64 threads
    gru_swapped_kernel<<<dim3(1300), dim3(64), 0, stream>>>(
        data, h0, w_ih, w_hh, b_ih, b_hh, out);
}